// Round 7
// baseline (538.129 us; speedup 1.0000x reference)
//
#include <hip/hip_runtime.h>
#include <hip/hip_bf16.h>
#include <stdint.h>

typedef __hip_bfloat16 bf16;
typedef __attribute__((ext_vector_type(8))) short short8;
typedef __attribute__((ext_vector_type(4))) short s16x4;
typedef __attribute__((ext_vector_type(4))) float floatx4;

#define MFMA16(a, b, c) __builtin_amdgcn_mfma_f32_16x16x32_bf16(a, b, c, 0, 0, 0)

__device__ __forceinline__ void async_lds16(const void* g, void* l) {
  __builtin_amdgcn_global_load_lds((__attribute__((address_space(1))) const void*)g,
                                   (__attribute__((address_space(3))) void*)l, 16, 0, 0);
}

// RNE-round two non-NaN floats to bf16, packed low|high into one u32
__device__ __forceinline__ unsigned rne2(float a, float b) {
  unsigned ua = __float_as_uint(a), ub = __float_as_uint(b);
  ua = ua + 0x7FFFu + ((ua >> 16) & 1u);
  ub = ub + 0x7FFFu + ((ub >> 16) & 1u);
  return (ua >> 16) | (ub & 0xFFFF0000u);
}

// ---------------- mask prep: int32 bool -> additive log2-bias (0 or -3000) ----
__global__ void prep_masks_k(const int* __restrict__ kv, const int* __restrict__ q,
                             float* __restrict__ kvB, float* __restrict__ qB) {
  int i = blockIdx.x * 256 + threadIdx.x;  // 4096 each
  kvB[i] = kv[i] ? 0.0f : -3000.0f;
  qB[i]  = q[i]  ? 0.0f : -3000.0f;
}

// ------- fused fp32 -> bf16 elementwise for x (4M) and K (4M), 4 elems/thread --
__global__ void cvt2_k(const float* __restrict__ a, bf16* __restrict__ da,
                       const float* __restrict__ b, bf16* __restrict__ db) {
  int gid = blockIdx.x;
  const float* s; bf16* d;
  if (gid < 4096) { s = a; d = da; } else { s = b; d = db; gid -= 4096; }
  int i = (gid * 256 + threadIdx.x) * 4;
  float4 v = *(const float4*)(s + i);
  uint2 o = {rne2(v.x, v.y), rne2(v.z, v.w)};
  *(uint2*)(d + i) = o;
}

// ------- LDS-tiled: fp32 src[m][R][C] -> bf16 dst[m][C][R], 64x64 tiles -------
// Write phase is row-coalesced: thread owns 16B chunks of one OUTPUT row.
__global__ __launch_bounds__(256) void cvt_transpose_k(const float* __restrict__ src,
                                                       bf16* __restrict__ dst, int R, int C) {
  __shared__ float tile[64][65];
  int m = blockIdx.z;
  int r0 = blockIdx.x * 64, c0 = blockIdx.y * 64;
  const float* s = src + (size_t)m * R * C;
  bf16* d = dst + (size_t)m * R * C;
  int t = threadIdx.x;
  int tr = t >> 2, tg = t & 3;
#pragma unroll
  for (int k = 0; k < 4; ++k) {
    int col = tg * 16 + k * 4;
    float4 v = *(const float4*)(s + (size_t)(r0 + tr) * C + c0 + col);
    tile[tr][col] = v.x; tile[tr][col + 1] = v.y; tile[tr][col + 2] = v.z; tile[tr][col + 3] = v.w;
  }
  __syncthreads();
  int orow = t >> 2, ch = t & 3;   // output row (= src col), 16B chunk
  bf16* drow = d + (size_t)(c0 + orow) * R + r0;
  uint4 w0, w1;
  w0.x = rne2(tile[ch * 8 + 0][orow], tile[ch * 8 + 1][orow]);
  w0.y = rne2(tile[ch * 8 + 2][orow], tile[ch * 8 + 3][orow]);
  w0.z = rne2(tile[ch * 8 + 4][orow], tile[ch * 8 + 5][orow]);
  w0.w = rne2(tile[ch * 8 + 6][orow], tile[ch * 8 + 7][orow]);
  w1.x = rne2(tile[32 + ch * 8 + 0][orow], tile[32 + ch * 8 + 1][orow]);
  w1.y = rne2(tile[32 + ch * 8 + 2][orow], tile[32 + ch * 8 + 3][orow]);
  w1.z = rne2(tile[32 + ch * 8 + 4][orow], tile[32 + ch * 8 + 5][orow]);
  w1.w = rne2(tile[32 + ch * 8 + 6][orow], tile[32 + ch * 8 + 7][orow]);
  *(uint4*)(drow + ch * 8) = w0;
  *(uint4*)(drow + 32 + ch * 8) = w1;
}

// ------- fused transposes for Wq and Wo (1024x1024), z selects which --------
__global__ __launch_bounds__(256) void cvtT_w_k(const float* __restrict__ w0p, bf16* __restrict__ d0,
                                                const float* __restrict__ w1p, bf16* __restrict__ d1) {
  __shared__ float tile[64][65];
  const float* s = blockIdx.z ? w1p : w0p;
  bf16* d = blockIdx.z ? d1 : d0;
  int r0 = blockIdx.x * 64, c0 = blockIdx.y * 64;
  int t = threadIdx.x;
  int tr = t >> 2, tg = t & 3;
#pragma unroll
  for (int k = 0; k < 4; ++k) {
    int col = tg * 16 + k * 4;
    float4 v = *(const float4*)(s + (size_t)(r0 + tr) * 1024 + c0 + col);
    tile[tr][col] = v.x; tile[tr][col + 1] = v.y; tile[tr][col + 2] = v.z; tile[tr][col + 3] = v.w;
  }
  __syncthreads();
  int orow = t >> 2, ch = t & 3;
  bf16* drow = d + (size_t)(c0 + orow) * 1024 + r0;
  uint4 a, b;
  a.x = rne2(tile[ch * 8 + 0][orow], tile[ch * 8 + 1][orow]);
  a.y = rne2(tile[ch * 8 + 2][orow], tile[ch * 8 + 3][orow]);
  a.z = rne2(tile[ch * 8 + 4][orow], tile[ch * 8 + 5][orow]);
  a.w = rne2(tile[ch * 8 + 6][orow], tile[ch * 8 + 7][orow]);
  b.x = rne2(tile[32 + ch * 8 + 0][orow], tile[32 + ch * 8 + 1][orow]);
  b.y = rne2(tile[32 + ch * 8 + 2][orow], tile[32 + ch * 8 + 3][orow]);
  b.z = rne2(tile[32 + ch * 8 + 4][orow], tile[32 + ch * 8 + 5][orow]);
  b.w = rne2(tile[32 + ch * 8 + 6][orow], tile[32 + ch * 8 + 7][orow]);
  *(uint4*)(drow + ch * 8) = a;
  *(uint4*)(drow + 32 + ch * 8) = b;
}

// ------- GEMM: C[M,N] = scale*(A[M,K] @ BT[N,K]^T), 128x64 tile, BK=64 -------
// Staging: A tile 128x64 = 8192 elems = 16 chunks of 512 -> 4/wave.
//          B tile  64x64 = 4096 elems =  8 chunks of 512 -> 2/wave.
__device__ __forceinline__ void storeC(bf16* C, size_t i, float v) { C[i] = __float2bfloat16(v); }
__device__ __forceinline__ void storeC(float* C, size_t i, float v) { C[i] = v; }

template <typename OT>
__global__ __launch_bounds__(256) void gemm_bt_k(const bf16* __restrict__ A,
                                                 const bf16* __restrict__ BT,
                                                 OT* __restrict__ C,
                                                 int M, int N, int K, float scale) {
  __shared__ __align__(16) bf16 As[128 * 64];
  __shared__ __align__(16) bf16 Bs[64 * 64];
  int tid = threadIdx.x;
  int wave = tid >> 6, lane = tid & 63;
  int quad = lane >> 4, lm = lane & 15;
  int wm = wave >> 1, wn = wave & 1;
  int row0 = blockIdx.y * 128, col0 = blockIdx.x * 64;

  floatx4 acc[4][2];
#pragma unroll
  for (int mt = 0; mt < 4; ++mt)
#pragma unroll
    for (int nt = 0; nt < 2; ++nt) acc[mt][nt] = (floatx4){0.f, 0.f, 0.f, 0.f};

  for (int k0 = 0; k0 < K; k0 += 64) {
    __syncthreads();
#pragma unroll
    for (int ch = 0; ch < 4; ++ch) {
      int e = (wave * 4 + ch) * 512 + lane * 8;
      async_lds16(A + (size_t)(row0 + (e >> 6)) * K + k0 + (e & 63), &As[(wave * 4 + ch) * 512]);
    }
#pragma unroll
    for (int ch = 0; ch < 2; ++ch) {
      int e = (wave * 2 + ch) * 512 + lane * 8;
      async_lds16(BT + (size_t)(col0 + (e >> 6)) * K + k0 + (e & 63), &Bs[(wave * 2 + ch) * 512]);
    }
    __syncthreads();
#pragma unroll
    for (int ks = 0; ks < 64; ks += 32) {
      short8 af[4], bfr[2];
#pragma unroll
      for (int mt = 0; mt < 4; ++mt)
        af[mt] = *(const short8*)&As[(wm * 64 + mt * 16 + lm) * 64 + ks + quad * 8];
#pragma unroll
      for (int nt = 0; nt < 2; ++nt)
        bfr[nt] = *(const short8*)&Bs[(wn * 32 + nt * 16 + lm) * 64 + ks + quad * 8];
#pragma unroll
      for (int mt = 0; mt < 4; ++mt)
#pragma unroll
        for (int nt = 0; nt < 2; ++nt)
          acc[mt][nt] = MFMA16(af[mt], bfr[nt], acc[mt][nt]);
    }
  }
#pragma unroll
  for (int mt = 0; mt < 4; ++mt)
#pragma unroll
    for (int nt = 0; nt < 2; ++nt)
#pragma unroll
      for (int j = 0; j < 4; ++j) {
        int rr = row0 + wm * 64 + mt * 16 + quad * 4 + j;
        int cc = col0 + wn * 32 + nt * 16 + lm;
        storeC(C, (size_t)rr * N + cc, acc[mt][nt][j] * scale);
      }
}

// ---------------- flash attention: LDS-staged K/V, kv-split-4 ----------------
// Grid (64,16,2): x = qblk(16) | slice(4). WG=4 waves; wave owns 32 q-rows,
// 512 kv per slice (8 iters). K/V tiles staged via global_load_lds with 16B
// XOR swizzle; softmax has no online max (log2-domain can't overflow fp32);
// masks = additive biases in QK acc init; row-sum l via ones-MFMA.
// Partials stored bf16 (unnormalized), combined by combine_k.
__global__ __launch_bounds__(256, 8) void attn_k(const bf16* __restrict__ Q,
                                                 const bf16* __restrict__ Km,
                                                 const bf16* __restrict__ VT,
                                                 const float* __restrict__ qB,
                                                 const float* __restrict__ kvB,
                                                 bf16* __restrict__ Opart,
                                                 float* __restrict__ lpart) {
  const float TINY = 9.313225746154785e-10f;  // 2^-30
  __shared__ __align__(16) bf16 Ks[64 * 64];
  __shared__ __align__(16) bf16 Vs[64 * 64];
  __shared__ __align__(16) float kvBs[512];

  int tid = threadIdx.x;
  int wave = tid >> 6, lane = tid & 63;
  int quad = lane >> 4, lm = lane & 15;
  int qb = blockIdx.x & 15, slice = blockIdx.x >> 4;  // slice 0..3
  int h = blockIdx.y, b = blockIdx.z;
  int q0 = qb * 128 + wave * 32;
  int kvbeg = slice * 512;

  const bf16* kbase = Km + (size_t)(b * 16 + h) * 2048 * 64;
  const bf16* vbase = VT + (size_t)(b * 16 + h) * 64 * 2048;
  const float* kvBb = kvB + b * 2048;

  // one-time: stage this slice's 512 kv biases (2 KB) into LDS
  if (wave < 2)
    async_lds16(kvBb + kvbeg + wave * 256 + lane * 4, &kvBs[wave * 256]);

  short8 aq[2][2];
  float qbias[2];
#pragma unroll
  for (int g = 0; g < 2; ++g) {
    const bf16* qp = Q + (size_t)(b * 2048 + q0 + g * 16 + lm) * 1024 + h * 64 + quad * 8;
    aq[g][0] = *(const short8*)qp;
    aq[g][1] = *(const short8*)(qp + 32);
    qbias[g] = qB[b * 2048 + q0 + g * 16 + lm];
  }

  short8 ones;
#pragma unroll
  for (int i = 0; i < 8; ++i) ones[i] = (short)0x3F80;  // bf16 1.0

  floatx4 o_acc[2][4];
  floatx4 l_acc[2];
#pragma unroll
  for (int g = 0; g < 2; ++g) {
    l_acc[g] = (floatx4){0.f, 0.f, 0.f, 0.f};
#pragma unroll
    for (int t = 0; t < 4; ++t) o_acc[g][t] = (floatx4){0.f, 0.f, 0.f, 0.f};
  }

  union S8U { short8 s8; s16x4 h[2]; unsigned u[4]; };

  for (int kv0 = kvbeg; kv0 < kvbeg + 512; kv0 += 64) {
    __syncthreads();  // previous iter's LDS readers done
#pragma unroll
    for (int c = 0; c < 2; ++c) {
      int o = (wave * 2 + c) * 1024 + lane * 16;  // byte offset in 8KB tile
      int r = o >> 7;                              // tile row 0..63
      int g16 = (o >> 4) & 7;                      // 16B chunk in row
      int sc = ((g16 ^ (r & 7)) * 8);              // swizzled source elem col
      async_lds16(kbase + (size_t)(kv0 + r) * 64 + sc, &Ks[(wave * 2 + c) * 512]);
      async_lds16(vbase + (size_t)r * 2048 + kv0 + sc, &Vs[(wave * 2 + c) * 512]);
    }
    __syncthreads();  // staging complete

    floatx4 kb4[4];
#pragma unroll
    for (int t = 0; t < 4; ++t)
      kb4[t] = *(const floatx4*)&kvBs[(kv0 - kvbeg) + t * 16 + quad * 4];

    // ---- S^T = K.Q^T per kv-tile t, fused exp2+pack into P^T B-frags ----
    S8U pf[2][2];
#pragma unroll
    for (int t = 0; t < 4; ++t) {
      int R = t * 16 + lm, sw = R & 7;
      short8 kf0 = *(const short8*)&Ks[R * 64 + ((quad ^ sw) * 8)];
      short8 kf1 = *(const short8*)&Ks[R * 64 + (((quad + 4) ^ sw) * 8)];
#pragma unroll
      for (int g = 0; g < 2; ++g) {
        floatx4 z;
#pragma unroll
        for (int j = 0; j < 4; ++j) z[j] = kb4[t][j] + qbias[g];
        z = MFMA16(kf0, aq[g][0], z);
        z = MFMA16(kf1, aq[g][1], z);
        float p0 = __builtin_amdgcn_exp2f(z[0]) + TINY;
        float p1 = __builtin_amdgcn_exp2f(z[1]) + TINY;
        float p2 = __builtin_amdgcn_exp2f(z[2]) + TINY;
        float p3 = __builtin_amdgcn_exp2f(z[3]) + TINY;
        pf[g][t >> 1].u[(t & 1) * 2 + 0] = rne2(p0, p1);
        pf[g][t >> 1].u[(t & 1) * 2 + 1] = rne2(p2, p3);
      }
    }
    // ---- O^T += V^T.P^T ; V frags from LDS with swizzled 8B gathers ----
#pragma unroll
    for (int t = 0; t < 4; ++t) {
      int D = t * 16 + lm, sw = D & 7;
      int hoff = (quad & 1) * 4, qh = quad >> 1;
      S8U vf0, vf1;
      vf0.h[0] = *(const s16x4*)&Vs[D * 64 + (((0 + qh) ^ sw) * 8) + hoff];
      vf0.h[1] = *(const s16x4*)&Vs[D * 64 + (((2 + qh) ^ sw) * 8) + hoff];
      vf1.h[0] = *(const s16x4*)&Vs[D * 64 + (((4 + qh) ^ sw) * 8) + hoff];
      vf1.h[1] = *(const s16x4*)&Vs[D * 64 + (((6 + qh) ^ sw) * 8) + hoff];
#pragma unroll
      for (int g = 0; g < 2; ++g) {
        o_acc[g][t] = MFMA16(vf0.s8, pf[g][0].s8, o_acc[g][t]);
        o_acc[g][t] = MFMA16(vf1.s8, pf[g][1].s8, o_acc[g][t]);
      }
    }
#pragma unroll
    for (int g = 0; g < 2; ++g) {
      l_acc[g] = MFMA16(ones, pf[g][0].s8, l_acc[g]);
      l_acc[g] = MFMA16(ones, pf[g][1].s8, l_acc[g]);
    }
  }
  // ---- epilogue: unnormalized bf16 partials, [slice][b][q][h*64+d] ----
  bf16* Op = Opart + (size_t)slice * (2u * 2048u * 1024u);
#pragma unroll
  for (int g = 0; g < 2; ++g) {
    int q = b * 2048 + q0 + g * 16 + lm;
    bf16* orow = Op + (size_t)q * 1024 + h * 64;
#pragma unroll
    for (int t = 0; t < 4; ++t) {
      uint2 ov = {rne2(o_acc[g][t][0], o_acc[g][t][1]),
                  rne2(o_acc[g][t][2], o_acc[g][t][3])};
      *(uint2*)(orow + t * 16 + quad * 4) = ov;
    }
    if (quad == 0)
      lpart[((size_t)slice * 4096 + (size_t)q) * 16 + h] = l_acc[g][0];
  }
}

// ---------------- combine: out = bf16(sum_s O_s / sum_s l_s) ----------------
__global__ void combine_k(const bf16* __restrict__ Opart, const float* __restrict__ lpart,
                          bf16* __restrict__ out) {
  int i = (blockIdx.x * 256 + threadIdx.x) * 8;  // over 2*2048*1024 elems
  int bq = i >> 10, h = (i >> 6) & 15;
  float l = lpart[bq * 16 + h] + lpart[65536 + bq * 16 + h] +
            lpart[131072 + bq * 16 + h] + lpart[196608 + bq * 16 + h];
  float rl = 1.0f / l;
  float acc[8];
#pragma unroll
  for (int e = 0; e < 8; ++e) acc[e] = 0.f;
#pragma unroll
  for (int s = 0; s < 4; ++s) {
    uint4 u = *(const uint4*)(Opart + s * 4194304 + i);
    acc[0] += __uint_as_float(u.x << 16); acc[1] += __uint_as_float(u.x & 0xFFFF0000u);
    acc[2] += __uint_as_float(u.y << 16); acc[3] += __uint_as_float(u.y & 0xFFFF0000u);
    acc[4] += __uint_as_float(u.z << 16); acc[5] += __uint_as_float(u.z & 0xFFFF0000u);
    acc[6] += __uint_as_float(u.w << 16); acc[7] += __uint_as_float(u.w & 0xFFFF0000u);
  }
  uint4 o = {rne2(acc[0] * rl, acc[1] * rl), rne2(acc[2] * rl, acc[3] * rl),
             rne2(acc[4] * rl, acc[5] * rl), rne2(acc[6] * rl, acc[7] * rl)};
  *(uint4*)(out + i) = o;
}

// ---------------- launch ----------------
extern "C" void kernel_launch(void* const* d_in, const int* in_sizes, int n_in,
                              void* d_out, int out_size, void* d_ws, size_t ws_size,
                              hipStream_t stream) {
  const float* x  = (const float*)d_in[0];   // [2,2048,1024] fp32
  const float* K  = (const float*)d_in[1];   // [2,16,2048,64] fp32
  const float* V  = (const float*)d_in[2];   // [2,16,2048,64] fp32
  const float* Wq = (const float*)d_in[3];   // [1024,1024] fp32
  const float* Wo = (const float*)d_in[4];   // [1024,1024] fp32
  const int* kvm  = (const int*)d_in[5];     // [2,1,1,2048] bool -> int32
  const int* qm   = (const int*)d_in[6];     // [2,1,2048,1] bool -> int32

  char* w = (char*)d_ws;
  bf16* xb    = (bf16*)(w);                        // 8 MB; reused as attnb by combine
  bf16* attnb = xb;
  bf16* Qb    = (bf16*)(w + (8u << 20));           // 8 MB (pre-scaled by log2e/sqrt(dk))
  bf16* Kb    = (bf16*)(w + (16u << 20));          // 8 MB
  bf16* VTb   = (bf16*)(w + (24u << 20));          // 8 MB [2,16,64,2048]
  bf16* WqT   = (bf16*)(w + (32u << 20));          // 2 MB
  bf16* WoT   = (bf16*)(w + (34u << 20));          // 2 MB
  float* qB   = (float*)(w + (36u << 20));         // 16 KB
  float* kvB  = (float*)(w + (36u << 20) + 16384); // 16 KB
  bf16* Opart = (bf16*)(w + (40u << 20));          // 32 MB [4][2][2048][1024] bf16
  float* lpart = (float*)(w + (72u << 20));        // 1 MB [4][4096][16] fp32

  const float SCL2 = 0.18033688011112042f;  // log2(e)/sqrt(64)

  prep_masks_k<<<16, 256, 0, stream>>>(kvm, qm, kvB, qB);
  cvt2_k<<<8192, 256, 0, stream>>>(x, xb, K, Kb);
  cvtT_w_k<<<dim3(16, 16, 2), 256, 0, stream>>>(Wq, WqT, Wo, WoT);
  cvt_transpose_k<<<dim3(32, 1, 32), 256, 0, stream>>>(V, VTb, 2048, 64);

  gemm_bt_k<bf16><<<dim3(16, 32), 256, 0, stream>>>(xb, WqT, Qb, 4096, 1024, 1024, SCL2);
  attn_k<<<dim3(64, 16, 2), 256, 0, stream>>>(Qb, Kb, VTb, qB, kvB, Opart, lpart);
  combine_k<<<2048, 256, 0, stream>>>(Opart, lpart, attnb);
  gemm_bt_k<float><<<dim3(16, 32), 256, 0, stream>>>(attnb, WoT, (float*)d_out, 4096, 1024, 1024, 1.0f);
}

// Round 8
// 216.143 us; speedup vs baseline: 2.4897x; 2.4897x over previous
//
#include <hip/hip_runtime.h>
#include <hip/hip_bf16.h>
#include <stdint.h>

typedef __hip_bfloat16 bf16;
typedef __attribute__((ext_vector_type(8))) short short8;
typedef __attribute__((ext_vector_type(4))) short s16x4;
typedef __attribute__((ext_vector_type(4))) float floatx4;

#define MFMA16(a, b, c) __builtin_amdgcn_mfma_f32_16x16x32_bf16(a, b, c, 0, 0, 0)

__device__ __forceinline__ void async_lds16(const void* g, void* l) {
  __builtin_amdgcn_global_load_lds((__attribute__((address_space(1))) const void*)g,
                                   (__attribute__((address_space(3))) void*)l, 16, 0, 0);
}

// RNE-round two non-NaN floats to bf16, packed low|high into one u32
__device__ __forceinline__ unsigned rne2(float a, float b) {
  unsigned ua = __float_as_uint(a), ub = __float_as_uint(b);
  ua = ua + 0x7FFFu + ((ua >> 16) & 1u);
  ub = ub + 0x7FFFu + ((ub >> 16) & 1u);
  return (ua >> 16) | (ub & 0xFFFF0000u);
}

// ---------------- mask prep: int32 bool -> additive log2-bias (0 or -3000) ----
__global__ void prep_masks_k(const int* __restrict__ kv, const int* __restrict__ q,
                             float* __restrict__ kvB, float* __restrict__ qB) {
  int i = blockIdx.x * 256 + threadIdx.x;  // 4096 each
  kvB[i] = kv[i] ? 0.0f : -3000.0f;
  qB[i]  = q[i]  ? 0.0f : -3000.0f;
}

// ------- fused fp32 -> bf16 elementwise for x (4M) and K (4M), 4 elems/thread --
__global__ void cvt2_k(const float* __restrict__ a, bf16* __restrict__ da,
                       const float* __restrict__ b, bf16* __restrict__ db) {
  int gid = blockIdx.x;
  const float* s; bf16* d;
  if (gid < 4096) { s = a; d = da; } else { s = b; d = db; gid -= 4096; }
  int i = (gid * 256 + threadIdx.x) * 4;
  float4 v = *(const float4*)(s + i);
  uint2 o = {rne2(v.x, v.y), rne2(v.z, v.w)};
  *(uint2*)(d + i) = o;
}

// ------- LDS-tiled: fp32 src[m][R][C] -> bf16 dst[m][C][R], 64x64 tiles -------
// Write phase is row-coalesced: thread owns 16B chunks of one OUTPUT row.
__global__ __launch_bounds__(256) void cvt_transpose_k(const float* __restrict__ src,
                                                       bf16* __restrict__ dst, int R, int C) {
  __shared__ float tile[64][65];
  int m = blockIdx.z;
  int r0 = blockIdx.x * 64, c0 = blockIdx.y * 64;
  const float* s = src + (size_t)m * R * C;
  bf16* d = dst + (size_t)m * R * C;
  int t = threadIdx.x;
  int tr = t >> 2, tg = t & 3;
#pragma unroll
  for (int k = 0; k < 4; ++k) {
    int col = tg * 16 + k * 4;
    float4 v = *(const float4*)(s + (size_t)(r0 + tr) * C + c0 + col);
    tile[tr][col] = v.x; tile[tr][col + 1] = v.y; tile[tr][col + 2] = v.z; tile[tr][col + 3] = v.w;
  }
  __syncthreads();
  int orow = t >> 2, ch = t & 3;   // output row (= src col), 16B chunk
  bf16* drow = d + (size_t)(c0 + orow) * R + r0;
  uint4 w0, w1;
  w0.x = rne2(tile[ch * 8 + 0][orow], tile[ch * 8 + 1][orow]);
  w0.y = rne2(tile[ch * 8 + 2][orow], tile[ch * 8 + 3][orow]);
  w0.z = rne2(tile[ch * 8 + 4][orow], tile[ch * 8 + 5][orow]);
  w0.w = rne2(tile[ch * 8 + 6][orow], tile[ch * 8 + 7][orow]);
  w1.x = rne2(tile[32 + ch * 8 + 0][orow], tile[32 + ch * 8 + 1][orow]);
  w1.y = rne2(tile[32 + ch * 8 + 2][orow], tile[32 + ch * 8 + 3][orow]);
  w1.z = rne2(tile[32 + ch * 8 + 4][orow], tile[32 + ch * 8 + 5][orow]);
  w1.w = rne2(tile[32 + ch * 8 + 6][orow], tile[32 + ch * 8 + 7][orow]);
  *(uint4*)(drow + ch * 8) = w0;
  *(uint4*)(drow + 32 + ch * 8) = w1;
}

// ------- fused transposes for Wq and Wo (1024x1024), z selects which --------
__global__ __launch_bounds__(256) void cvtT_w_k(const float* __restrict__ w0p, bf16* __restrict__ d0,
                                                const float* __restrict__ w1p, bf16* __restrict__ d1) {
  __shared__ float tile[64][65];
  const float* s = blockIdx.z ? w1p : w0p;
  bf16* d = blockIdx.z ? d1 : d0;
  int r0 = blockIdx.x * 64, c0 = blockIdx.y * 64;
  int t = threadIdx.x;
  int tr = t >> 2, tg = t & 3;
#pragma unroll
  for (int k = 0; k < 4; ++k) {
    int col = tg * 16 + k * 4;
    float4 v = *(const float4*)(s + (size_t)(r0 + tr) * 1024 + c0 + col);
    tile[tr][col] = v.x; tile[tr][col + 1] = v.y; tile[tr][col + 2] = v.z; tile[tr][col + 3] = v.w;
  }
  __syncthreads();
  int orow = t >> 2, ch = t & 3;
  bf16* drow = d + (size_t)(c0 + orow) * 1024 + r0;
  uint4 a, b;
  a.x = rne2(tile[ch * 8 + 0][orow], tile[ch * 8 + 1][orow]);
  a.y = rne2(tile[ch * 8 + 2][orow], tile[ch * 8 + 3][orow]);
  a.z = rne2(tile[ch * 8 + 4][orow], tile[ch * 8 + 5][orow]);
  a.w = rne2(tile[ch * 8 + 6][orow], tile[ch * 8 + 7][orow]);
  b.x = rne2(tile[32 + ch * 8 + 0][orow], tile[32 + ch * 8 + 1][orow]);
  b.y = rne2(tile[32 + ch * 8 + 2][orow], tile[32 + ch * 8 + 3][orow]);
  b.z = rne2(tile[32 + ch * 8 + 4][orow], tile[32 + ch * 8 + 5][orow]);
  b.w = rne2(tile[32 + ch * 8 + 6][orow], tile[32 + ch * 8 + 7][orow]);
  *(uint4*)(drow + ch * 8) = a;
  *(uint4*)(drow + 32 + ch * 8) = b;
}

// ------- GEMM: C[M,N] = scale*(A[M,K] @ BT[N,K]^T), 128x64 tile, BK=64 -------
__device__ __forceinline__ void storeC(bf16* C, size_t i, float v) { C[i] = __float2bfloat16(v); }
__device__ __forceinline__ void storeC(float* C, size_t i, float v) { C[i] = v; }

template <typename OT>
__global__ __launch_bounds__(256) void gemm_bt_k(const bf16* __restrict__ A,
                                                 const bf16* __restrict__ BT,
                                                 OT* __restrict__ C,
                                                 int M, int N, int K, float scale) {
  __shared__ __align__(16) bf16 As[128 * 64];
  __shared__ __align__(16) bf16 Bs[64 * 64];
  int tid = threadIdx.x;
  int wave = tid >> 6, lane = tid & 63;
  int quad = lane >> 4, lm = lane & 15;
  int wm = wave >> 1, wn = wave & 1;
  int row0 = blockIdx.y * 128, col0 = blockIdx.x * 64;

  floatx4 acc[4][2];
#pragma unroll
  for (int mt = 0; mt < 4; ++mt)
#pragma unroll
    for (int nt = 0; nt < 2; ++nt) acc[mt][nt] = (floatx4){0.f, 0.f, 0.f, 0.f};

  for (int k0 = 0; k0 < K; k0 += 64) {
    __syncthreads();
#pragma unroll
    for (int ch = 0; ch < 4; ++ch) {
      int e = (wave * 4 + ch) * 512 + lane * 8;
      async_lds16(A + (size_t)(row0 + (e >> 6)) * K + k0 + (e & 63), &As[(wave * 4 + ch) * 512]);
    }
#pragma unroll
    for (int ch = 0; ch < 2; ++ch) {
      int e = (wave * 2 + ch) * 512 + lane * 8;
      async_lds16(BT + (size_t)(col0 + (e >> 6)) * K + k0 + (e & 63), &Bs[(wave * 2 + ch) * 512]);
    }
    __syncthreads();
#pragma unroll
    for (int ks = 0; ks < 64; ks += 32) {
      short8 af[4], bfr[2];
#pragma unroll
      for (int mt = 0; mt < 4; ++mt)
        af[mt] = *(const short8*)&As[(wm * 64 + mt * 16 + lm) * 64 + ks + quad * 8];
#pragma unroll
      for (int nt = 0; nt < 2; ++nt)
        bfr[nt] = *(const short8*)&Bs[(wn * 32 + nt * 16 + lm) * 64 + ks + quad * 8];
#pragma unroll
      for (int mt = 0; mt < 4; ++mt)
#pragma unroll
        for (int nt = 0; nt < 2; ++nt)
          acc[mt][nt] = MFMA16(af[mt], bfr[nt], acc[mt][nt]);
    }
  }
#pragma unroll
  for (int mt = 0; mt < 4; ++mt)
#pragma unroll
    for (int nt = 0; nt < 2; ++nt)
#pragma unroll
      for (int j = 0; j < 4; ++j) {
        int rr = row0 + wm * 64 + mt * 16 + quad * 4 + j;
        int cc = col0 + wn * 32 + nt * 16 + lm;
        storeC(C, (size_t)rr * N + cc, acc[mt][nt][j] * scale);
      }
}

// ---------------- flash attention: LDS-staged K/V, kv-split-4 ----------------
// Grid (64,16,2): x = qblk(16) | slice(4). WG=4 waves; wave owns 32 q-rows,
// 512 kv per slice (8 iters). LB(256,4): gfx950 unified VGPR/AGPR file —
// an 8-waves/EU bound caps regs at 64 incl. accumulators and spills (R7:
// 1.7 GB/dispatch scratch traffic, 375 us). With <=64 regs HW reaches
// 8 blocks/CU on its own (LDS 18.4 KB x 8 = 147 KB < 160).
__global__ __launch_bounds__(256, 4) void attn_k(const bf16* __restrict__ Q,
                                                 const bf16* __restrict__ Km,
                                                 const bf16* __restrict__ VT,
                                                 const float* __restrict__ qB,
                                                 const float* __restrict__ kvB,
                                                 bf16* __restrict__ Opart,
                                                 float* __restrict__ lpart) {
  const float TINY = 9.313225746154785e-10f;  // 2^-30
  __shared__ __align__(16) bf16 Ks[64 * 64];
  __shared__ __align__(16) bf16 Vs[64 * 64];
  __shared__ __align__(16) float kvBs[512];

  int tid = threadIdx.x;
  int wave = tid >> 6, lane = tid & 63;
  int quad = lane >> 4, lm = lane & 15;
  int qb = blockIdx.x & 15, slice = blockIdx.x >> 4;  // slice 0..3
  int h = blockIdx.y, b = blockIdx.z;
  int q0 = qb * 128 + wave * 32;
  int kvbeg = slice * 512;

  const bf16* kbase = Km + (size_t)(b * 16 + h) * 2048 * 64;
  const bf16* vbase = VT + (size_t)(b * 16 + h) * 64 * 2048;
  const float* kvBb = kvB + b * 2048;

  // one-time: stage this slice's 512 kv biases (2 KB) into LDS
  if (wave < 2)
    async_lds16(kvBb + kvbeg + wave * 256 + lane * 4, &kvBs[wave * 256]);

  short8 aq[2][2];
  float qbias[2];
#pragma unroll
  for (int g = 0; g < 2; ++g) {
    const bf16* qp = Q + (size_t)(b * 2048 + q0 + g * 16 + lm) * 1024 + h * 64 + quad * 8;
    aq[g][0] = *(const short8*)qp;
    aq[g][1] = *(const short8*)(qp + 32);
    qbias[g] = qB[b * 2048 + q0 + g * 16 + lm];
  }

  short8 ones;
#pragma unroll
  for (int i = 0; i < 8; ++i) ones[i] = (short)0x3F80;  // bf16 1.0

  floatx4 o_acc[2][4];
  floatx4 l_acc[2];
#pragma unroll
  for (int g = 0; g < 2; ++g) {
    l_acc[g] = (floatx4){0.f, 0.f, 0.f, 0.f};
#pragma unroll
    for (int t = 0; t < 4; ++t) o_acc[g][t] = (floatx4){0.f, 0.f, 0.f, 0.f};
  }

  union S8U { short8 s8; s16x4 h[2]; unsigned u[4]; };

  for (int kv0 = kvbeg; kv0 < kvbeg + 512; kv0 += 64) {
    __syncthreads();  // previous iter's LDS readers done
#pragma unroll
    for (int c = 0; c < 2; ++c) {
      int o = (wave * 2 + c) * 1024 + lane * 16;  // byte offset in 8KB tile
      int r = o >> 7;                              // tile row 0..63
      int g16 = (o >> 4) & 7;                      // 16B chunk in row
      int sc = ((g16 ^ (r & 7)) * 8);              // swizzled source elem col
      async_lds16(kbase + (size_t)(kv0 + r) * 64 + sc, &Ks[(wave * 2 + c) * 512]);
      async_lds16(vbase + (size_t)r * 2048 + kv0 + sc, &Vs[(wave * 2 + c) * 512]);
    }
    __syncthreads();  // staging complete

    floatx4 kb4[4];
#pragma unroll
    for (int t = 0; t < 4; ++t)
      kb4[t] = *(const floatx4*)&kvBs[(kv0 - kvbeg) + t * 16 + quad * 4];

    // ---- S^T = K.Q^T per kv-tile t, fused exp2+pack into P^T B-frags ----
    S8U pf[2][2];
#pragma unroll
    for (int t = 0; t < 4; ++t) {
      int R = t * 16 + lm, sw = R & 7;
      short8 kf0 = *(const short8*)&Ks[R * 64 + ((quad ^ sw) * 8)];
      short8 kf1 = *(const short8*)&Ks[R * 64 + (((quad + 4) ^ sw) * 8)];
#pragma unroll
      for (int g = 0; g < 2; ++g) {
        floatx4 z;
#pragma unroll
        for (int j = 0; j < 4; ++j) z[j] = kb4[t][j] + qbias[g];
        z = MFMA16(kf0, aq[g][0], z);
        z = MFMA16(kf1, aq[g][1], z);
        float p0 = __builtin_amdgcn_exp2f(z[0]) + TINY;
        float p1 = __builtin_amdgcn_exp2f(z[1]) + TINY;
        float p2 = __builtin_amdgcn_exp2f(z[2]) + TINY;
        float p3 = __builtin_amdgcn_exp2f(z[3]) + TINY;
        pf[g][t >> 1].u[(t & 1) * 2 + 0] = rne2(p0, p1);
        pf[g][t >> 1].u[(t & 1) * 2 + 1] = rne2(p2, p3);
      }
    }
    // ---- O^T += V^T.P^T ; V frags from LDS with swizzled 8B gathers ----
#pragma unroll
    for (int t = 0; t < 4; ++t) {
      int D = t * 16 + lm, sw = D & 7;
      int hoff = (quad & 1) * 4, qh = quad >> 1;
      S8U vf0, vf1;
      vf0.h[0] = *(const s16x4*)&Vs[D * 64 + (((0 + qh) ^ sw) * 8) + hoff];
      vf0.h[1] = *(const s16x4*)&Vs[D * 64 + (((2 + qh) ^ sw) * 8) + hoff];
      vf1.h[0] = *(const s16x4*)&Vs[D * 64 + (((4 + qh) ^ sw) * 8) + hoff];
      vf1.h[1] = *(const s16x4*)&Vs[D * 64 + (((6 + qh) ^ sw) * 8) + hoff];
#pragma unroll
      for (int g = 0; g < 2; ++g) {
        o_acc[g][t] = MFMA16(vf0.s8, pf[g][0].s8, o_acc[g][t]);
        o_acc[g][t] = MFMA16(vf1.s8, pf[g][1].s8, o_acc[g][t]);
      }
    }
#pragma unroll
    for (int g = 0; g < 2; ++g) {
      l_acc[g] = MFMA16(ones, pf[g][0].s8, l_acc[g]);
      l_acc[g] = MFMA16(ones, pf[g][1].s8, l_acc[g]);
    }
  }
  // ---- epilogue: unnormalized bf16 partials, [slice][b][q][h*64+d] ----
  bf16* Op = Opart + (size_t)slice * (2u * 2048u * 1024u);
#pragma unroll
  for (int g = 0; g < 2; ++g) {
    int q = b * 2048 + q0 + g * 16 + lm;
    bf16* orow = Op + (size_t)q * 1024 + h * 64;
#pragma unroll
    for (int t = 0; t < 4; ++t) {
      uint2 ov = {rne2(o_acc[g][t][0], o_acc[g][t][1]),
                  rne2(o_acc[g][t][2], o_acc[g][t][3])};
      *(uint2*)(orow + t * 16 + quad * 4) = ov;
    }
    if (quad == 0)
      lpart[((size_t)slice * 4096 + (size_t)q) * 16 + h] = l_acc[g][0];
  }
}

// ---------------- combine: out = bf16(sum_s O_s / sum_s l_s) ----------------
__global__ void combine_k(const bf16* __restrict__ Opart, const float* __restrict__ lpart,
                          bf16* __restrict__ out) {
  int i = (blockIdx.x * 256 + threadIdx.x) * 8;  // over 2*2048*1024 elems
  int bq = i >> 10, h = (i >> 6) & 15;
  float l = lpart[bq * 16 + h] + lpart[65536 + bq * 16 + h] +
            lpart[131072 + bq * 16 + h] + lpart[196608 + bq * 16 + h];
  float rl = 1.0f / l;
  float acc[8];
#pragma unroll
  for (int e = 0; e < 8; ++e) acc[e] = 0.f;
#pragma unroll
  for (int s = 0; s < 4; ++s) {
    uint4 u = *(const uint4*)(Opart + s * 4194304 + i);
    acc[0] += __uint_as_float(u.x << 16); acc[1] += __uint_as_float(u.x & 0xFFFF0000u);
    acc[2] += __uint_as_float(u.y << 16); acc[3] += __uint_as_float(u.y & 0xFFFF0000u);
    acc[4] += __uint_as_float(u.z << 16); acc[5] += __uint_as_float(u.z & 0xFFFF0000u);
    acc[6] += __uint_as_float(u.w << 16); acc[7] += __uint_as_float(u.w & 0xFFFF0000u);
  }
  uint4 o = {rne2(acc[0] * rl, acc[1] * rl), rne2(acc[2] * rl, acc[3] * rl),
             rne2(acc[4] * rl, acc[5] * rl), rne2(acc[6] * rl, acc[7] * rl)};
  *(uint4*)(out + i) = o;
}

// ---------------- launch ----------------
extern "C" void kernel_launch(void* const* d_in, const int* in_sizes, int n_in,
                              void* d_out, int out_size, void* d_ws, size_t ws_size,
                              hipStream_t stream) {
  const float* x  = (const float*)d_in[0];   // [2,2048,1024] fp32
  const float* K  = (const float*)d_in[1];   // [2,16,2048,64] fp32
  const float* V  = (const float*)d_in[2];   // [2,16,2048,64] fp32
  const float* Wq = (const float*)d_in[3];   // [1024,1024] fp32
  const float* Wo = (const float*)d_in[4];   // [1024,1024] fp32
  const int* kvm  = (const int*)d_in[5];     // [2,1,1,2048] bool -> int32
  const int* qm   = (const int*)d_in[6];     // [2,1,2048,1] bool -> int32

  char* w = (char*)d_ws;
  bf16* xb    = (bf16*)(w);                        // 8 MB; reused as attnb by combine
  bf16* attnb = xb;
  bf16* Qb    = (bf16*)(w + (8u << 20));           // 8 MB (pre-scaled by log2e/sqrt(dk))
  bf16* Kb    = (bf16*)(w + (16u << 20));          // 8 MB
  bf16* VTb   = (bf16*)(w + (24u << 20));          // 8 MB [2,16,64,2048]
  bf16* WqT   = (bf16*)(w + (32u << 20));          // 2 MB
  bf16* WoT   = (bf16*)(w + (34u << 20));          // 2 MB
  float* qB   = (float*)(w + (36u << 20));         // 16 KB
  float* kvB  = (float*)(w + (36u << 20) + 16384); // 16 KB
  bf16* Opart = (bf16*)(w + (40u << 20));          // 16 MB [4][2][2048][1024] bf16
  float* lpart = (float*)(w + (72u << 20));        // 1 MB [4][4096][16] fp32

  const float SCL2 = 0.18033688011112042f;  // log2(e)/sqrt(64)

  prep_masks_k<<<16, 256, 0, stream>>>(kvm, qm, kvB, qB);
  cvt2_k<<<8192, 256, 0, stream>>>(x, xb, K, Kb);
  cvtT_w_k<<<dim3(16, 16, 2), 256, 0, stream>>>(Wq, WqT, Wo, WoT);
  cvt_transpose_k<<<dim3(32, 1, 32), 256, 0, stream>>>(V, VTb, 2048, 64);

  gemm_bt_k<bf16><<<dim3(16, 32), 256, 0, stream>>>(xb, WqT, Qb, 4096, 1024, 1024, SCL2);
  attn_k<<<dim3(64, 16, 2), 256, 0, stream>>>(Qb, Kb, VTb, qB, kvB, Opart, lpart);
  combine_k<<<2048, 256, 0, stream>>>(Opart, lpart, attnb);
  gemm_bt_k<float><<<dim3(16, 32), 256, 0, stream>>>(attnb, WoT, (float*)d_out, 4096, 1024, 1024, 1.0f);
}

// Round 9
// 204.592 us; speedup vs baseline: 2.6303x; 1.0565x over previous
//
#include <hip/hip_runtime.h>
#include <hip/hip_bf16.h>
#include <stdint.h>

typedef __hip_bfloat16 bf16;
typedef __attribute__((ext_vector_type(8))) short short8;
typedef __attribute__((ext_vector_type(4))) short s16x4;
typedef __attribute__((ext_vector_type(4))) float floatx4;

#define MFMA16(a, b, c) __builtin_amdgcn_mfma_f32_16x16x32_bf16(a, b, c, 0, 0, 0)

__device__ __forceinline__ void async_lds16(const void* g, void* l) {
  __builtin_amdgcn_global_load_lds((__attribute__((address_space(1))) const void*)g,
                                   (__attribute__((address_space(3))) void*)l, 16, 0, 0);
}

// RNE-round two non-NaN floats to bf16, packed low|high into one u32
__device__ __forceinline__ unsigned rne2(float a, float b) {
  unsigned ua = __float_as_uint(a), ub = __float_as_uint(b);
  ua = ua + 0x7FFFu + ((ua >> 16) & 1u);
  ub = ub + 0x7FFFu + ((ub >> 16) & 1u);
  return (ua >> 16) | (ub & 0xFFFF0000u);
}

// ------------- fused prep: cvt(x,K) | transpose(Wq,Wo,V) | masks -------------
// Block ranges: [0,8192) cvt; [8192,8704) W transposes; [8704,9728) V transpose;
// [9728,9744) mask biases. Branches are block-uniform.
__global__ __launch_bounds__(256) void prep_k(const float* __restrict__ x, bf16* __restrict__ xb,
                                              const float* __restrict__ Kf, bf16* __restrict__ Kb,
                                              const float* __restrict__ Wq, bf16* __restrict__ WqT,
                                              const float* __restrict__ Wo, bf16* __restrict__ WoT,
                                              const float* __restrict__ V, bf16* __restrict__ VTb,
                                              const int* __restrict__ kvm, const int* __restrict__ qm,
                                              float* __restrict__ kvB, float* __restrict__ qB) {
  __shared__ float tile[64][65];
  int bid = blockIdx.x, tid = threadIdx.x;
  if (bid < 8192) {  // fp32 -> bf16 elementwise, 4 elems/thread
    const float* s; bf16* d; int g = bid;
    if (g < 4096) { s = x; d = xb; } else { s = Kf; d = Kb; g -= 4096; }
    int i = (g * 256 + tid) * 4;
    float4 v = *(const float4*)(s + i);
    uint2 o = {rne2(v.x, v.y), rne2(v.z, v.w)};
    *(uint2*)(d + i) = o;
    return;
  }
  if (bid < 9744 - 16) {  // 64x64 convert+transpose tiles
    const float* s; bf16* d; int r0, c0, R, C;
    if (bid < 8704) {
      int idx = bid - 8192;
      s = (idx >> 8) ? Wo : Wq; d = (idx >> 8) ? WoT : WqT;
      int rem = idx & 255;
      r0 = (rem & 15) * 64; c0 = (rem >> 4) * 64; R = 1024; C = 1024;
    } else {
      int idx = bid - 8704;
      int m = idx >> 5;
      s = V + (size_t)m * 2048 * 64; d = VTb + (size_t)m * 2048 * 64;
      r0 = (idx & 31) * 64; c0 = 0; R = 2048; C = 64;
    }
    int tr = tid >> 2, tg = tid & 3;
#pragma unroll
    for (int k = 0; k < 4; ++k) {
      int col = tg * 16 + k * 4;
      float4 v = *(const float4*)(s + (size_t)(r0 + tr) * C + c0 + col);
      tile[tr][col] = v.x; tile[tr][col + 1] = v.y;
      tile[tr][col + 2] = v.z; tile[tr][col + 3] = v.w;
    }
    __syncthreads();
    int orow = tid >> 2, ch = tid & 3;  // output row (= src col), 16B chunks
    bf16* drow = d + (size_t)(c0 + orow) * R + r0;
    uint4 w0, w1;
    w0.x = rne2(tile[ch * 8 + 0][orow], tile[ch * 8 + 1][orow]);
    w0.y = rne2(tile[ch * 8 + 2][orow], tile[ch * 8 + 3][orow]);
    w0.z = rne2(tile[ch * 8 + 4][orow], tile[ch * 8 + 5][orow]);
    w0.w = rne2(tile[ch * 8 + 6][orow], tile[ch * 8 + 7][orow]);
    w1.x = rne2(tile[32 + ch * 8 + 0][orow], tile[32 + ch * 8 + 1][orow]);
    w1.y = rne2(tile[32 + ch * 8 + 2][orow], tile[32 + ch * 8 + 3][orow]);
    w1.z = rne2(tile[32 + ch * 8 + 4][orow], tile[32 + ch * 8 + 5][orow]);
    w1.w = rne2(tile[32 + ch * 8 + 6][orow], tile[32 + ch * 8 + 7][orow]);
    *(uint4*)(drow + ch * 8) = w0;
    *(uint4*)(drow + 32 + ch * 8) = w1;
    return;
  }
  int i = (bid - (9744 - 16)) * 256 + tid;  // mask -> additive log2 bias
  kvB[i] = kvm[i] ? 0.0f : -3000.0f;
  qB[i]  = qm[i]  ? 0.0f : -3000.0f;
}

// ------- GEMM: C[M,N] = scale*(A[M,K] @ BT[N,K]^T), 64x64 tile, BK=64 -------
// 1024 WGs at M=4096,N=1024 -> 4 blocks/CU. LDS staged via global_load_lds
// with XOR source swizzle (16B chunk c' = c ^ (row&7)): BK=64 row stride is
// 128 B = 32 banks, unswizzled b128 frag reads would be 16-lane same-bank.
__device__ __forceinline__ void storeC(bf16* C, size_t i, float v) { C[i] = __float2bfloat16(v); }
__device__ __forceinline__ void storeC(float* C, size_t i, float v) { C[i] = v; }

template <typename OT>
__global__ __launch_bounds__(256) void gemm_bt_k(const bf16* __restrict__ A,
                                                 const bf16* __restrict__ BT,
                                                 OT* __restrict__ C,
                                                 int M, int N, int K, float scale) {
  __shared__ __align__(16) bf16 As[64 * 64];
  __shared__ __align__(16) bf16 Bs[64 * 64];
  int tid = threadIdx.x;
  int wave = tid >> 6, lane = tid & 63;
  int quad = lane >> 4, lm = lane & 15;
  int wm = wave >> 1, wn = wave & 1;
  int row0 = blockIdx.y * 64, col0 = blockIdx.x * 64;

  floatx4 acc[2][2];
#pragma unroll
  for (int mt = 0; mt < 2; ++mt)
#pragma unroll
    for (int nt = 0; nt < 2; ++nt) acc[mt][nt] = (floatx4){0.f, 0.f, 0.f, 0.f};

  for (int k0 = 0; k0 < K; k0 += 64) {
    __syncthreads();
#pragma unroll
    for (int ch = 0; ch < 2; ++ch) {  // A: 8 chunks of 512 elems -> 2/wave
      int e = (wave * 2 + ch) * 512 + lane * 8;
      int r = e >> 6, c16 = (e & 63) >> 3;
      int sc = (c16 ^ (r & 7)) * 8;
      async_lds16(A + (size_t)(row0 + r) * K + k0 + sc, &As[(wave * 2 + ch) * 512]);
    }
#pragma unroll
    for (int ch = 0; ch < 2; ++ch) {  // B: same geometry
      int e = (wave * 2 + ch) * 512 + lane * 8;
      int r = e >> 6, c16 = (e & 63) >> 3;
      int sc = (c16 ^ (r & 7)) * 8;
      async_lds16(BT + (size_t)(col0 + r) * K + k0 + sc, &Bs[(wave * 2 + ch) * 512]);
    }
    __syncthreads();
    int sw = lm & 7;
#pragma unroll
    for (int ks = 0; ks < 64; ks += 32) {
      short8 af[2], bfr[2];
#pragma unroll
      for (int mt = 0; mt < 2; ++mt) {
        int R = wm * 32 + mt * 16 + lm;
        af[mt] = *(const short8*)&As[R * 64 + ((((ks >> 3) + quad) ^ sw) * 8)];
      }
#pragma unroll
      for (int nt = 0; nt < 2; ++nt) {
        int R = wn * 32 + nt * 16 + lm;
        bfr[nt] = *(const short8*)&Bs[R * 64 + ((((ks >> 3) + quad) ^ sw) * 8)];
      }
#pragma unroll
      for (int mt = 0; mt < 2; ++mt)
#pragma unroll
        for (int nt = 0; nt < 2; ++nt)
          acc[mt][nt] = MFMA16(af[mt], bfr[nt], acc[mt][nt]);
    }
  }
#pragma unroll
  for (int mt = 0; mt < 2; ++mt)
#pragma unroll
    for (int nt = 0; nt < 2; ++nt)
#pragma unroll
      for (int j = 0; j < 4; ++j) {
        int rr = row0 + wm * 32 + mt * 16 + quad * 4 + j;
        int cc = col0 + wn * 32 + nt * 16 + lm;
        storeC(C, (size_t)rr * N + cc, acc[mt][nt][j] * scale);
      }
}

// ---------------- flash attention: LDS-staged K/V, no kv-split ----------------
// Grid (32,16,2). WG = 4 waves x 16 q-rows = 64 q; full 2048-kv sweep (32 iters).
// K/V tiles staged via global_load_lds with XOR source swizzle; kv mask biases
// staged to LDS once. No online max (log2-domain scores can't overflow fp32);
// masks = additive biases in QK acc init; l via ones-MFMA; epilogue normalizes
// and writes bf16 directly (no partials, no combine pass).
// LB(256,4): R7 lesson — higher waves/EU bound spills accumulators (unified
// VGPR/AGPR file); grid gives exactly 4 blocks/CU.
__global__ __launch_bounds__(256, 4) void attn_k(const bf16* __restrict__ Q,
                                                 const bf16* __restrict__ Km,
                                                 const bf16* __restrict__ VT,
                                                 const float* __restrict__ qB,
                                                 const float* __restrict__ kvB,
                                                 bf16* __restrict__ O) {
  const float TINY = 9.313225746154785e-10f;  // 2^-30
  __shared__ __align__(16) bf16 Ks[64 * 64];
  __shared__ __align__(16) bf16 Vs[64 * 64];
  __shared__ __align__(16) float kvBs[2048];

  int tid = threadIdx.x;
  int wave = tid >> 6, lane = tid & 63;
  int quad = lane >> 4, lm = lane & 15;
  int qb = blockIdx.x, h = blockIdx.y, b = blockIdx.z;
  int q0 = qb * 64 + wave * 16;

  const bf16* kbase = Km + (size_t)(b * 16 + h) * 2048 * 64;
  const bf16* vbase = VT + (size_t)(b * 16 + h) * 64 * 2048;
  const float* kvBb = kvB + b * 2048;

  // one-time: stage all 2048 kv biases (8 KB) into LDS
#pragma unroll
  for (int c = 0; c < 2; ++c)
    async_lds16(kvBb + (wave * 2 + c) * 256 + lane * 4, &kvBs[(wave * 2 + c) * 256]);

  short8 aq0, aq1;
  float qbias;
  {
    const bf16* qp = Q + (size_t)(b * 2048 + q0 + lm) * 1024 + h * 64 + quad * 8;
    aq0 = *(const short8*)qp;
    aq1 = *(const short8*)(qp + 32);
    qbias = qB[b * 2048 + q0 + lm];
  }

  short8 ones;
#pragma unroll
  for (int i = 0; i < 8; ++i) ones[i] = (short)0x3F80;  // bf16 1.0

  floatx4 o_acc[4];
  floatx4 l_acc = (floatx4){0.f, 0.f, 0.f, 0.f};
#pragma unroll
  for (int t = 0; t < 4; ++t) o_acc[t] = (floatx4){0.f, 0.f, 0.f, 0.f};

  union S8U { short8 s8; s16x4 h[2]; unsigned u[4]; };

  for (int kv0 = 0; kv0 < 2048; kv0 += 64) {
    __syncthreads();  // previous iter's LDS readers done (covers kvBs 1st time)
#pragma unroll
    for (int c = 0; c < 2; ++c) {
      int o = (wave * 2 + c) * 1024 + lane * 16;  // byte offset in 8KB tile
      int r = o >> 7;                              // tile row 0..63
      int g16 = (o >> 4) & 7;                      // 16B chunk in row
      int sc = ((g16 ^ (r & 7)) * 8);              // swizzled source elem col
      async_lds16(kbase + (size_t)(kv0 + r) * 64 + sc, &Ks[(wave * 2 + c) * 512]);
      async_lds16(vbase + (size_t)r * 2048 + kv0 + sc, &Vs[(wave * 2 + c) * 512]);
    }
    __syncthreads();  // staging complete

    // ---- S^T = K.Q^T per kv-tile t, fused exp2+pack into P^T B-frags ----
    S8U pf[2];
#pragma unroll
    for (int t = 0; t < 4; ++t) {
      int R = t * 16 + lm, sw = lm & 7;
      short8 kf0 = *(const short8*)&Ks[R * 64 + ((quad ^ sw) * 8)];
      short8 kf1 = *(const short8*)&Ks[R * 64 + (((quad + 4) ^ sw) * 8)];
      floatx4 z = *(const floatx4*)&kvBs[kv0 + t * 16 + quad * 4];
#pragma unroll
      for (int j = 0; j < 4; ++j) z[j] += qbias;
      z = MFMA16(kf0, aq0, z);
      z = MFMA16(kf1, aq1, z);
      float p0 = __builtin_amdgcn_exp2f(z[0]) + TINY;
      float p1 = __builtin_amdgcn_exp2f(z[1]) + TINY;
      float p2 = __builtin_amdgcn_exp2f(z[2]) + TINY;
      float p3 = __builtin_amdgcn_exp2f(z[3]) + TINY;
      pf[t >> 1].u[(t & 1) * 2 + 0] = rne2(p0, p1);
      pf[t >> 1].u[(t & 1) * 2 + 1] = rne2(p2, p3);
    }
    // ---- O^T += V^T.P^T ; V frags from LDS with swizzled 8B gathers ----
#pragma unroll
    for (int t = 0; t < 4; ++t) {
      int D = t * 16 + lm, sw = lm & 7;
      int hoff = (quad & 1) * 4, qh = quad >> 1;
      S8U vf0, vf1;
      vf0.h[0] = *(const s16x4*)&Vs[D * 64 + (((0 + qh) ^ sw) * 8) + hoff];
      vf0.h[1] = *(const s16x4*)&Vs[D * 64 + (((2 + qh) ^ sw) * 8) + hoff];
      vf1.h[0] = *(const s16x4*)&Vs[D * 64 + (((4 + qh) ^ sw) * 8) + hoff];
      vf1.h[1] = *(const s16x4*)&Vs[D * 64 + (((6 + qh) ^ sw) * 8) + hoff];
      o_acc[t] = MFMA16(vf0.s8, pf[0].s8, o_acc[t]);
      o_acc[t] = MFMA16(vf1.s8, pf[1].s8, o_acc[t]);
    }
    l_acc = MFMA16(ones, pf[0].s8, l_acc);
    l_acc = MFMA16(ones, pf[1].s8, l_acc);
  }
  // ---- epilogue: normalize, write bf16 [b][q][h*64+d] directly ----
  float rl = 1.0f / l_acc[0];
  bf16* orow = O + (size_t)(b * 2048 + q0 + lm) * 1024 + h * 64;
#pragma unroll
  for (int t = 0; t < 4; ++t) {
    uint2 ov = {rne2(o_acc[t][0] * rl, o_acc[t][1] * rl),
                rne2(o_acc[t][2] * rl, o_acc[t][3] * rl)};
    *(uint2*)(orow + t * 16 + quad * 4) = ov;
  }
}

// ---------------- launch ----------------
extern "C" void kernel_launch(void* const* d_in, const int* in_sizes, int n_in,
                              void* d_out, int out_size, void* d_ws, size_t ws_size,
                              hipStream_t stream) {
  const float* x  = (const float*)d_in[0];   // [2,2048,1024] fp32
  const float* K  = (const float*)d_in[1];   // [2,16,2048,64] fp32
  const float* V  = (const float*)d_in[2];   // [2,16,2048,64] fp32
  const float* Wq = (const float*)d_in[3];   // [1024,1024] fp32
  const float* Wo = (const float*)d_in[4];   // [1024,1024] fp32
  const int* kvm  = (const int*)d_in[5];     // [2,1,1,2048] bool -> int32
  const int* qm   = (const int*)d_in[6];     // [2,1,2048,1] bool -> int32

  char* w = (char*)d_ws;
  bf16* xb    = (bf16*)(w);                        // 8 MB; reused as attnb (xb dead after gemm1)
  bf16* attnb = xb;
  bf16* Qb    = (bf16*)(w + (8u << 20));           // 8 MB (pre-scaled by log2e/sqrt(dk))
  bf16* Kb    = (bf16*)(w + (16u << 20));          // 8 MB
  bf16* VTb   = (bf16*)(w + (24u << 20));          // 8 MB [2,16,64,2048]
  bf16* WqT   = (bf16*)(w + (32u << 20));          // 2 MB
  bf16* WoT   = (bf16*)(w + (34u << 20));          // 2 MB
  float* qB   = (float*)(w + (36u << 20));         // 16 KB
  float* kvB  = (float*)(w + (36u << 20) + 16384); // 16 KB

  const float SCL2 = 0.18033688011112042f;  // log2(e)/sqrt(64)

  prep_k<<<9744, 256, 0, stream>>>(x, xb, K, Kb, Wq, WqT, Wo, WoT, V, VTb, kvm, qm, kvB, qB);
  gemm_bt_k<bf16><<<dim3(16, 64), 256, 0, stream>>>(xb, WqT, Qb, 4096, 1024, 1024, SCL2);
  attn_k<<<dim3(32, 16, 2), 256, 0, stream>>>(Qb, Kb, VTb, qB, kvB, attnb);
  gemm_bt_k<float><<<dim3(16, 64), 256, 0, stream>>>(attnb, WoT, (float*)d_out, 4096, 1024, 1024, 1.0f);
}

// Round 10
// 200.758 us; speedup vs baseline: 2.6805x; 1.0191x over previous
//
#include <hip/hip_runtime.h>
#include <hip/hip_bf16.h>
#include <stdint.h>

typedef __hip_bfloat16 bf16;
typedef __attribute__((ext_vector_type(8))) short short8;
typedef __attribute__((ext_vector_type(4))) short s16x4;
typedef __attribute__((ext_vector_type(4))) float floatx4;

#define MFMA16(a, b, c) __builtin_amdgcn_mfma_f32_16x16x32_bf16(a, b, c, 0, 0, 0)
// s_waitcnt imm: vmcnt[3:0], expcnt[6:4]=7 (no wait), lgkmcnt[11:8]=15 (no wait)
#define WAIT_VM4 3956  // 4 | (7<<4) | (15<<8)
#define WAIT_VM0 3952  // 0 | (7<<4) | (15<<8)

__device__ __forceinline__ void async_lds16(const void* g, void* l) {
  __builtin_amdgcn_global_load_lds((__attribute__((address_space(1))) const void*)g,
                                   (__attribute__((address_space(3))) void*)l, 16, 0, 0);
}

// RNE-round two non-NaN floats to bf16, packed low|high into one u32
__device__ __forceinline__ unsigned rne2(float a, float b) {
  unsigned ua = __float_as_uint(a), ub = __float_as_uint(b);
  ua = ua + 0x7FFFu + ((ua >> 16) & 1u);
  ub = ub + 0x7FFFu + ((ub >> 16) & 1u);
  return (ua >> 16) | (ub & 0xFFFF0000u);
}

// ------------- fused prep: cvt(x,K) | transpose(Wq,Wo,V) | masks -------------
__global__ __launch_bounds__(256) void prep_k(const float* __restrict__ x, bf16* __restrict__ xb,
                                              const float* __restrict__ Kf, bf16* __restrict__ Kb,
                                              const float* __restrict__ Wq, bf16* __restrict__ WqT,
                                              const float* __restrict__ Wo, bf16* __restrict__ WoT,
                                              const float* __restrict__ V, bf16* __restrict__ VTb,
                                              const int* __restrict__ kvm, const int* __restrict__ qm,
                                              float* __restrict__ kvB, float* __restrict__ qB) {
  __shared__ float tile[64][65];
  int bid = blockIdx.x, tid = threadIdx.x;
  if (bid < 8192) {  // fp32 -> bf16 elementwise, 4 elems/thread
    const float* s; bf16* d; int g = bid;
    if (g < 4096) { s = x; d = xb; } else { s = Kf; d = Kb; g -= 4096; }
    int i = (g * 256 + tid) * 4;
    float4 v = *(const float4*)(s + i);
    uint2 o = {rne2(v.x, v.y), rne2(v.z, v.w)};
    *(uint2*)(d + i) = o;
    return;
  }
  if (bid < 9744 - 16) {  // 64x64 convert+transpose tiles
    const float* s; bf16* d; int r0, c0, R, C;
    if (bid < 8704) {
      int idx = bid - 8192;
      s = (idx >> 8) ? Wo : Wq; d = (idx >> 8) ? WoT : WqT;
      int rem = idx & 255;
      r0 = (rem & 15) * 64; c0 = (rem >> 4) * 64; R = 1024; C = 1024;
    } else {
      int idx = bid - 8704;
      int m = idx >> 5;
      s = V + (size_t)m * 2048 * 64; d = VTb + (size_t)m * 2048 * 64;
      r0 = (idx & 31) * 64; c0 = 0; R = 2048; C = 64;
    }
    int tr = tid >> 2, tg = tid & 3;
#pragma unroll
    for (int k = 0; k < 4; ++k) {
      int col = tg * 16 + k * 4;
      float4 v = *(const float4*)(s + (size_t)(r0 + tr) * C + c0 + col);
      tile[tr][col] = v.x; tile[tr][col + 1] = v.y;
      tile[tr][col + 2] = v.z; tile[tr][col + 3] = v.w;
    }
    __syncthreads();
    int orow = tid >> 2, ch = tid & 3;
    bf16* drow = d + (size_t)(c0 + orow) * R + r0;
    uint4 w0, w1;
    w0.x = rne2(tile[ch * 8 + 0][orow], tile[ch * 8 + 1][orow]);
    w0.y = rne2(tile[ch * 8 + 2][orow], tile[ch * 8 + 3][orow]);
    w0.z = rne2(tile[ch * 8 + 4][orow], tile[ch * 8 + 5][orow]);
    w0.w = rne2(tile[ch * 8 + 6][orow], tile[ch * 8 + 7][orow]);
    w1.x = rne2(tile[32 + ch * 8 + 0][orow], tile[32 + ch * 8 + 1][orow]);
    w1.y = rne2(tile[32 + ch * 8 + 2][orow], tile[32 + ch * 8 + 3][orow]);
    w1.z = rne2(tile[32 + ch * 8 + 4][orow], tile[32 + ch * 8 + 5][orow]);
    w1.w = rne2(tile[32 + ch * 8 + 6][orow], tile[32 + ch * 8 + 7][orow]);
    *(uint4*)(drow + ch * 8) = w0;
    *(uint4*)(drow + 32 + ch * 8) = w1;
    return;
  }
  int i = (bid - (9744 - 16)) * 256 + tid;  // mask -> additive log2 bias
  kvB[i] = kvm[i] ? 0.0f : -3000.0f;
  qB[i]  = qm[i]  ? 0.0f : -3000.0f;
}

// ------- GEMM: C[M,N] = scale*(A @ BT^T), 64x64 tile, BK=64, LDS dbuf -------
// Double-buffered staging with raw s_barrier + s_waitcnt vmcnt(4): the wait
// covers only the PREVIOUS iteration's 4 loads (already landed), not the
// just-issued prefetch — removes the per-iter vmcnt(0) barrier drain.
// Invariant: no other VMEM in flight inside the loop (keeps vmcnt exact).
__device__ __forceinline__ void storeC(bf16* C, size_t i, float v) { C[i] = __float2bfloat16(v); }
__device__ __forceinline__ void storeC(float* C, size_t i, float v) { C[i] = v; }

template <typename OT>
__global__ __launch_bounds__(256) void gemm_bt_k(const bf16* __restrict__ A,
                                                 const bf16* __restrict__ BT,
                                                 OT* __restrict__ C,
                                                 int M, int N, int K, float scale) {
  __shared__ __align__(16) bf16 As[2][64 * 64];
  __shared__ __align__(16) bf16 Bs[2][64 * 64];
  int tid = threadIdx.x;
  int wave = tid >> 6, lane = tid & 63;
  int quad = lane >> 4, lm = lane & 15;
  int wm = wave >> 1, wn = wave & 1;
  int row0 = blockIdx.y * 64, col0 = blockIdx.x * 64;

  floatx4 acc[2][2];
#pragma unroll
  for (int mt = 0; mt < 2; ++mt)
#pragma unroll
    for (int nt = 0; nt < 2; ++nt) acc[mt][nt] = (floatx4){0.f, 0.f, 0.f, 0.f};

  auto stageAB = [&](int buf, int k0) {
#pragma unroll
    for (int ch = 0; ch < 2; ++ch) {  // 4 loads/wave total (2 A + 2 B)
      int e = (wave * 2 + ch) * 512 + lane * 8;
      int r = e >> 6, c16 = (e & 63) >> 3;
      int sc = (c16 ^ (r & 7)) * 8;  // XOR source swizzle for bank spread
      async_lds16(A + (size_t)(row0 + r) * K + k0 + sc, &As[buf][(wave * 2 + ch) * 512]);
      async_lds16(BT + (size_t)(col0 + r) * K + k0 + sc, &Bs[buf][(wave * 2 + ch) * 512]);
    }
  };

  int niter = K >> 6;
  stageAB(0, 0);
  for (int i = 0; i < niter; ++i) {
    __builtin_amdgcn_s_barrier();  // all waves done reading buf (i+1)&1
    if (i + 1 < niter) {
      stageAB((i + 1) & 1, (i + 1) << 6);
      __builtin_amdgcn_s_waitcnt(WAIT_VM4);  // cur buffer's loads (prev iter) done
    } else {
      __builtin_amdgcn_s_waitcnt(WAIT_VM0);
    }
    __builtin_amdgcn_s_barrier();  // every wave's cur staging landed
    const bf16* Ac = As[i & 1];
    const bf16* Bc = Bs[i & 1];
    int sw = lm & 7;
#pragma unroll
    for (int ks = 0; ks < 64; ks += 32) {
      short8 af[2], bfr[2];
#pragma unroll
      for (int mt = 0; mt < 2; ++mt) {
        int R = wm * 32 + mt * 16 + lm;
        af[mt] = *(const short8*)&Ac[R * 64 + ((((ks >> 3) + quad) ^ sw) * 8)];
      }
#pragma unroll
      for (int nt = 0; nt < 2; ++nt) {
        int R = wn * 32 + nt * 16 + lm;
        bfr[nt] = *(const short8*)&Bc[R * 64 + ((((ks >> 3) + quad) ^ sw) * 8)];
      }
#pragma unroll
      for (int mt = 0; mt < 2; ++mt)
#pragma unroll
        for (int nt = 0; nt < 2; ++nt)
          acc[mt][nt] = MFMA16(af[mt], bfr[nt], acc[mt][nt]);
    }
  }
#pragma unroll
  for (int mt = 0; mt < 2; ++mt)
#pragma unroll
    for (int nt = 0; nt < 2; ++nt)
#pragma unroll
      for (int j = 0; j < 4; ++j) {
        int rr = row0 + wm * 32 + mt * 16 + quad * 4 + j;
        int cc = col0 + wn * 32 + nt * 16 + lm;
        storeC(C, (size_t)rr * N + cc, acc[mt][nt][j] * scale);
      }
}

// ------- flash attention: dbuf LDS-staged K/V, full kv sweep, direct out -----
// Grid (32,16,2). WG = 4 waves x 16 q-rows; 32 kv iters. Same dbuf+vmcnt(4)
// pattern as the GEMM. kv biases staged to LDS via ds_write BEFORE the loop
// (keeps in-loop VMEM = staging only, so the manual vmcnt stays exact).
// LDS 40 KB -> 4 blocks/CU = 160 KiB exactly. LB(256,4): R7 lesson (unified
// VGPR/AGPR file — higher bound spills accumulators).
__global__ __launch_bounds__(256, 4) void attn_k(const bf16* __restrict__ Q,
                                                 const bf16* __restrict__ Km,
                                                 const bf16* __restrict__ VT,
                                                 const float* __restrict__ qB,
                                                 const float* __restrict__ kvB,
                                                 bf16* __restrict__ O) {
  const float TINY = 9.313225746154785e-10f;  // 2^-30
  __shared__ __align__(16) bf16 Ks[2][64 * 64];
  __shared__ __align__(16) bf16 Vs[2][64 * 64];
  __shared__ __align__(16) float kvBs[2048];

  int tid = threadIdx.x;
  int wave = tid >> 6, lane = tid & 63;
  int quad = lane >> 4, lm = lane & 15;
  int qb = blockIdx.x, h = blockIdx.y, b = blockIdx.z;
  int q0 = qb * 64 + wave * 16;

  const bf16* kbase = Km + (size_t)(b * 16 + h) * 2048 * 64;
  const bf16* vbase = VT + (size_t)(b * 16 + h) * 64 * 2048;
  const float* kvBb = kvB + b * 2048;

  // stage all 2048 kv biases to LDS with plain loads + ds_write
  {
    float4 v0 = *(const float4*)(kvBb + tid * 8);
    float4 v1 = *(const float4*)(kvBb + tid * 8 + 4);
    *(float4*)&kvBs[tid * 8] = v0;
    *(float4*)&kvBs[tid * 8 + 4] = v1;
  }

  short8 aq0, aq1;
  float qbias;
  {
    const bf16* qp = Q + (size_t)(b * 2048 + q0 + lm) * 1024 + h * 64 + quad * 8;
    aq0 = *(const short8*)qp;
    aq1 = *(const short8*)(qp + 32);
    qbias = qB[b * 2048 + q0 + lm];
  }

  short8 ones;
#pragma unroll
  for (int i = 0; i < 8; ++i) ones[i] = (short)0x3F80;  // bf16 1.0

  floatx4 o_acc[4];
  floatx4 l_acc = (floatx4){0.f, 0.f, 0.f, 0.f};
#pragma unroll
  for (int t = 0; t < 4; ++t) o_acc[t] = (floatx4){0.f, 0.f, 0.f, 0.f};

  union S8U { short8 s8; s16x4 h[2]; unsigned u[4]; };

  auto stageKV = [&](int buf, int kv0) {
#pragma unroll
    for (int c = 0; c < 2; ++c) {  // 4 loads/wave total (2 K + 2 V)
      int o = (wave * 2 + c) * 1024 + lane * 16;  // byte offset in 8KB tile
      int r = o >> 7;                              // tile row 0..63
      int g16 = (o >> 4) & 7;                      // 16B chunk in row
      int sc = ((g16 ^ (r & 7)) * 8);              // swizzled source elem col
      async_lds16(kbase + (size_t)(kv0 + r) * 64 + sc, &Ks[buf][(wave * 2 + c) * 512]);
      async_lds16(vbase + (size_t)r * 2048 + kv0 + sc, &Vs[buf][(wave * 2 + c) * 512]);
    }
  };

  __syncthreads();  // biases visible to all waves; drains Q/bias loads (vmcnt=0)
  stageKV(0, 0);
  for (int i = 0; i < 32; ++i) {
    int kv0 = i * 64;
    __builtin_amdgcn_s_barrier();  // all waves done reading buf (i+1)&1
    if (i + 1 < 32) {
      stageKV((i + 1) & 1, kv0 + 64);
      __builtin_amdgcn_s_waitcnt(WAIT_VM4);  // cur buffer's loads (prev iter) done
    } else {
      __builtin_amdgcn_s_waitcnt(WAIT_VM0);
    }
    __builtin_amdgcn_s_barrier();  // every wave's cur staging landed
    const bf16* Kc = Ks[i & 1];
    const bf16* Vc = Vs[i & 1];

    // ---- S^T = K.Q^T per kv-tile t, fused exp2+pack into P^T B-frags ----
    S8U pf[2];
#pragma unroll
    for (int t = 0; t < 4; ++t) {
      int R = t * 16 + lm, sw = lm & 7;
      short8 kf0 = *(const short8*)&Kc[R * 64 + ((quad ^ sw) * 8)];
      short8 kf1 = *(const short8*)&Kc[R * 64 + (((quad + 4) ^ sw) * 8)];
      floatx4 z = *(const floatx4*)&kvBs[kv0 + t * 16 + quad * 4];
#pragma unroll
      for (int j = 0; j < 4; ++j) z[j] += qbias;
      z = MFMA16(kf0, aq0, z);
      z = MFMA16(kf1, aq1, z);
      float p0 = __builtin_amdgcn_exp2f(z[0]) + TINY;
      float p1 = __builtin_amdgcn_exp2f(z[1]) + TINY;
      float p2 = __builtin_amdgcn_exp2f(z[2]) + TINY;
      float p3 = __builtin_amdgcn_exp2f(z[3]) + TINY;
      pf[t >> 1].u[(t & 1) * 2 + 0] = rne2(p0, p1);
      pf[t >> 1].u[(t & 1) * 2 + 1] = rne2(p2, p3);
    }
    // ---- O^T += V^T.P^T ; V frags from LDS with swizzled 8B gathers ----
#pragma unroll
    for (int t = 0; t < 4; ++t) {
      int D = t * 16 + lm, sw = lm & 7;
      int hoff = (quad & 1) * 4, qh = quad >> 1;
      S8U vf0, vf1;
      vf0.h[0] = *(const s16x4*)&Vc[D * 64 + (((0 + qh) ^ sw) * 8) + hoff];
      vf0.h[1] = *(const s16x4*)&Vc[D * 64 + (((2 + qh) ^ sw) * 8) + hoff];
      vf1.h[0] = *(const s16x4*)&Vc[D * 64 + (((4 + qh) ^ sw) * 8) + hoff];
      vf1.h[1] = *(const s16x4*)&Vc[D * 64 + (((6 + qh) ^ sw) * 8) + hoff];
      o_acc[t] = MFMA16(vf0.s8, pf[0].s8, o_acc[t]);
      o_acc[t] = MFMA16(vf1.s8, pf[1].s8, o_acc[t]);
    }
    l_acc = MFMA16(ones, pf[0].s8, l_acc);
    l_acc = MFMA16(ones, pf[1].s8, l_acc);
  }
  // ---- epilogue: normalize, write bf16 [b][q][h*64+d] directly ----
  float rl = 1.0f / l_acc[0];
  bf16* orow = O + (size_t)(b * 2048 + q0 + lm) * 1024 + h * 64;
#pragma unroll
  for (int t = 0; t < 4; ++t) {
    uint2 ov = {rne2(o_acc[t][0] * rl, o_acc[t][1] * rl),
                rne2(o_acc[t][2] * rl, o_acc[t][3] * rl)};
    *(uint2*)(orow + t * 16 + quad * 4) = ov;
  }
}

// ---------------- launch ----------------
extern "C" void kernel_launch(void* const* d_in, const int* in_sizes, int n_in,
                              void* d_out, int out_size, void* d_ws, size_t ws_size,
                              hipStream_t stream) {
  const float* x  = (const float*)d_in[0];   // [2,2048,1024] fp32
  const float* K  = (const float*)d_in[1];   // [2,16,2048,64] fp32
  const float* V  = (const float*)d_in[2];   // [2,16,2048,64] fp32
  const float* Wq = (const float*)d_in[3];   // [1024,1024] fp32
  const float* Wo = (const float*)d_in[4];   // [1024,1024] fp32
  const int* kvm  = (const int*)d_in[5];     // [2,1,1,2048] bool -> int32
  const int* qm   = (const int*)d_in[6];     // [2,1,2048,1] bool -> int32

  char* w = (char*)d_ws;
  bf16* xb    = (bf16*)(w);                        // 8 MB; reused as attnb (xb dead after gemm1)
  bf16* attnb = xb;
  bf16* Qb    = (bf16*)(w + (8u << 20));           // 8 MB (pre-scaled by log2e/sqrt(dk))
  bf16* Kb    = (bf16*)(w + (16u << 20));          // 8 MB
  bf16* VTb   = (bf16*)(w + (24u << 20));          // 8 MB [2,16,64,2048]
  bf16* WqT   = (bf16*)(w + (32u << 20));          // 2 MB
  bf16* WoT   = (bf16*)(w + (34u << 20));          // 2 MB
  float* qB   = (float*)(w + (36u << 20));         // 16 KB
  float* kvB  = (float*)(w + (36u << 20) + 16384); // 16 KB

  const float SCL2 = 0.18033688011112042f;  // log2(e)/sqrt(64)

  prep_k<<<9744, 256, 0, stream>>>(x, xb, K, Kb, Wq, WqT, Wo, WoT, V, VTb, kvm, qm, kvB, qB);
  gemm_bt_k<bf16><<<dim3(16, 64), 256, 0, stream>>>(xb, WqT, Qb, 4096, 1024, 1024, SCL2);
  attn_k<<<dim3(32, 16, 2), 256, 0, stream>>>(Qb, Kb, VTb, qB, kvB, attnb);
  gemm_bt_k<float><<<dim3(16, 64), 256, 0, stream>>>(attnb, WoT, (float*)d_out, 4096, 1024, 1024, 1.0f);
}